// Round 1
// baseline (62.101 us; speedup 1.0000x reference)
//
#include <hip/hip_runtime.h>
#include <stdint.h>
#include <stddef.h>

typedef __bf16 bf16;
typedef __attribute__((ext_vector_type(8))) __bf16 bf16x8;
typedef __attribute__((ext_vector_type(4))) __bf16 bf16x4;
typedef __attribute__((ext_vector_type(4))) float  f32x4;

// ---------------- geometry ----------------
// B = 262144 samples. node: (B,19,4) f32, edge: (B,36,4) f32.
// compact first-4 nonzero rows of each -> x[32]; L1 32->256 relu; L2 256->128 relu;
// L3 128->34; log_softmax. Output (B,34) f32.
//
// Weight image (bf16, fragment-linear, built by prep_kernel in d_ws):
//   frag(layer,nt,kk) = 1024B: lane l holds 16B = W[k0..k0+8)[n],
//   n = nt*16 + (l&15), k0 = kk*32 + 8*(l>>4).
#define W1OFF  0               // 16 frags
#define W2OFF  (16*1024)       // 64 frags
#define W3OFF  (80*1024)       // 12 frags (N padded 34->48 with zeros)
#define BOFF   (92*1024)       // b1[256] f32, b2[128], b3[48] (pad 0) = 1728B
#define IMGSZ  (92*1024 + 1728)
#define NCHUNK (IMGSZ/16)      // 5996 16B chunks
#define PERW   3072            // per-wave LDS: x dbuf 2*1024 + stage 1024
#define LDSSZ  (IMGSZ + 8*PERW)  // 120512 B

// swizzle for [16 rows][64B] bf16 tiles: XOR 16B-chunk index with (row>>1)&3
#define SWZ(s) ((((s)>>1)&3)<<4)

__global__ void prep_kernel(const float* __restrict__ W1, const float* __restrict__ b1,
                            const float* __restrict__ W2, const float* __restrict__ b2,
                            const float* __restrict__ W3, const float* __restrict__ b3,
                            char* __restrict__ img)
{
  int tid = blockIdx.x * 256 + threadIdx.x;
  if (tid < 92 * 64) {                       // 5888 weight chunks
    int fid = tid >> 6, l = tid & 63;
    int m = l & 15, gg = l >> 4;
    const float* W; int stride, n, k0;
    if (fid < 16)      { W = W1; stride = 256; n = fid * 16 + m;            k0 = gg * 8; }
    else if (fid < 80) { int f = fid - 16; W = W2; stride = 128; n = (f >> 3) * 16 + m; k0 = (f & 7) * 32 + gg * 8; }
    else               { int f = fid - 80; W = W3; stride = 34;  n = (f >> 2) * 16 + m; k0 = (f & 3) * 32 + gg * 8; }
    bf16x8 v;
    #pragma unroll
    for (int j = 0; j < 8; ++j) {
      float x = (stride == 34 && n >= 34) ? 0.f : W[(size_t)(k0 + j) * stride + n];
      v[j] = (bf16)x;
    }
    *(bf16x8*)(img + (size_t)tid * 16) = v;
  } else if (tid < 92 * 64 + 432) {          // biases, flat f32
    int i = tid - 92 * 64;
    float v;
    if (i < 256)      v = b1[i];
    else if (i < 384) v = b2[i - 256];
    else              { int j = i - 384; v = (j < 34) ? b3[j] : 0.f; }
    ((float*)(img + BOFF))[i] = v;
  }
}

__global__ __launch_bounds__(512, 2) void mlp_kernel(
    const float* __restrict__ node, const float* __restrict__ edge,
    const char* __restrict__ img, float* __restrict__ out)
{
  __shared__ __align__(16) char sm[LDSSZ];
  const int tid  = threadIdx.x;
  const int lane = tid & 63;
  const int w    = tid >> 6;
  const int blk  = blockIdx.x;

  // stage weight image to LDS (coalesced 16B copies), one barrier total
  for (int c = tid; c < NCHUNK; c += 512)
    *(f32x4*)(sm + (size_t)c * 16) = *(const f32x4*)(img + (size_t)c * 16);
  __syncthreads();

  char* const xb0 = sm + IMGSZ + w * PERW;   // x tile buf A (1KB)
  char* const xb1 = xb0 + 1024;              // x tile buf B
  char* const stg = xb0 + 2048;              // inter-layer stage (1KB)
  const float* const b1p = (const float*)(sm + BOFF);
  const float* const b2p = b1p + 256;
  const float* const b3p = b1p + 384;

  const int g   = lane >> 4;   // mfma 16-lane group
  const int m16 = lane & 15;   // sample col (compute) / weight row
  const int cl  = lane & 3;    // compaction lane within sample
  const int sl  = lane >> 2;   // compaction sample-in-tile (0..15)

  const float4* const np = (const float4*)node;   // 19 float4 per sample
  const float4* const ep = (const float4*)edge;   // 36 float4 per sample
  const f32x4 zf = {0.f, 0.f, 0.f, 0.f};

  float4 nf[5], ef[9];

  auto issue_loads = [&](int sbase) {
    const int s = sbase + sl;
    #pragma unroll
    for (int i = 0; i < 5; ++i) {
      const int r = cl + 4 * i;
      nf[i] = (r < 19) ? np[(size_t)s * 19 + r] : make_float4(0.f, 0.f, 0.f, 0.f);
    }
    #pragma unroll
    for (int i = 0; i < 9; ++i)
      ef[i] = ep[(size_t)s * 36 + cl + 4 * i];
  };

  auto compact = [&](char* dst) {
    uint32_t nm = 0; unsigned long long em = 0;
    #pragma unroll
    for (int i = 0; i < 5; ++i) {
      const int r = cl + 4 * i;
      if (r < 19 && (nf[i].x != 0.f || nf[i].y != 0.f || nf[i].z != 0.f || nf[i].w != 0.f))
        nm |= (1u << r);
    }
    #pragma unroll
    for (int i = 0; i < 9; ++i) {
      const int r = cl + 4 * i;
      if (ef[i].x != 0.f || ef[i].y != 0.f || ef[i].z != 0.f || ef[i].w != 0.f)
        em |= (1ull << r);
    }
    nm |= __shfl_xor(nm, 1); nm |= __shfl_xor(nm, 2);
    em |= __shfl_xor(em, 1); em |= __shfl_xor(em, 2);
    // zero-init my two 8B slots of the row (covers all 8 slots across 4 lanes);
    // lockstep guarantees zeros land before any data write below.
    bf16x4 zb; zb[0] = (bf16)0.f; zb[1] = (bf16)0.f; zb[2] = (bf16)0.f; zb[3] = (bf16)0.f;
    *(bf16x4*)(dst + sl * 64 + ((8 * cl)      ^ SWZ(sl))) = zb;
    *(bf16x4*)(dst + sl * 64 + ((8 * cl + 32) ^ SWZ(sl))) = zb;
    #pragma unroll
    for (int i = 0; i < 5; ++i) {
      const int r = cl + 4 * i;
      if (r < 19 && ((nm >> r) & 1u)) {
        const int slot = __popc(nm & ((1u << r) - 1u));
        if (slot < 4) {
          bf16x4 pk; pk[0] = (bf16)nf[i].x; pk[1] = (bf16)nf[i].y; pk[2] = (bf16)nf[i].z; pk[3] = (bf16)nf[i].w;
          *(bf16x4*)(dst + sl * 64 + ((8 * slot) ^ SWZ(sl))) = pk;
        }
      }
    }
    #pragma unroll
    for (int i = 0; i < 9; ++i) {
      const int r = cl + 4 * i;
      if ((em >> r) & 1ull) {
        const int slot = __popcll(em & ((1ull << r) - 1ull));
        if (slot < 4) {
          bf16x4 pk; pk[0] = (bf16)ef[i].x; pk[1] = (bf16)ef[i].y; pk[2] = (bf16)ef[i].z; pk[3] = (bf16)ef[i].w;
          *(bf16x4*)(dst + sl * 64 + ((32 + 8 * slot) ^ SWZ(sl))) = pk;
        }
      }
    }
  };

  // prologue: pass 0 data
  issue_loads(blk * 1024 + w * 16);
  compact(xb0);

  #pragma unroll 1
  for (int p = 0; p < 8; ++p) {
    char* const xb = (p & 1) ? xb1 : xb0;
    char* const xn = (p & 1) ? xb0 : xb1;
    const int S = blk * 1024 + p * 128 + w * 16;
    const bool pf = (p < 7);

    if (pf) issue_loads(S + 128);            // prefetch next pass
    asm volatile("" ::: "memory");           // keep loads issued before compute

    // x B-fragment: lane holds x[s=m16][8g .. 8g+8)
    bf16x8 xf = *(const bf16x8*)(xb + m16 * 64 + ((16 * g) ^ SWZ(m16)));

    // ---- L1 (32->256) fused into L2 (256->128) per 32-feature chunk ----
    f32x4 acc2[8];
    #pragma unroll
    for (int i = 0; i < 8; ++i) acc2[i] = zf;

    #pragma unroll
    for (int kk = 0; kk < 8; ++kk) {
      #pragma unroll
      for (int t = 0; t < 2; ++t) {
        const int nt1 = kk * 2 + t;
        bf16x8 wf = *(const bf16x8*)(sm + W1OFF + nt1 * 1024 + lane * 16);
        f32x4 d = __builtin_amdgcn_mfma_f32_16x16x32_bf16(wf, xf, zf, 0, 0, 0);
        f32x4 b = *(const f32x4*)(b1p + nt1 * 16 + 4 * g);
        bf16x4 pk;
        #pragma unroll
        for (int r = 0; r < 4; ++r) pk[r] = (bf16)fmaxf(d[r] + b[r], 0.f);
        // D is [feature][sample]: lane has 4 consecutive features of sample m16
        *(bf16x4*)(stg + m16 * 64 + ((32 * t + 8 * g) ^ SWZ(m16))) = pk;
      }
      bf16x8 sf = *(const bf16x8*)(stg + m16 * 64 + ((16 * g) ^ SWZ(m16)));
      #pragma unroll
      for (int nt2 = 0; nt2 < 8; ++nt2) {
        bf16x8 wf = *(const bf16x8*)(sm + W2OFF + (nt2 * 8 + kk) * 1024 + lane * 16);
        acc2[nt2] = __builtin_amdgcn_mfma_f32_16x16x32_bf16(wf, sf, acc2[nt2], 0, 0, 0);
      }
    }

    // ---- L2 out -> L3 (128->48 padded) ----
    f32x4 acc3[3];
    #pragma unroll
    for (int i = 0; i < 3; ++i) acc3[i] = zf;

    #pragma unroll
    for (int k2 = 0; k2 < 4; ++k2) {
      #pragma unroll
      for (int t = 0; t < 2; ++t) {
        const int nt2 = k2 * 2 + t;
        f32x4 b = *(const f32x4*)(b2p + nt2 * 16 + 4 * g);
        bf16x4 pk;
        #pragma unroll
        for (int r = 0; r < 4; ++r) pk[r] = (bf16)fmaxf(acc2[nt2][r] + b[r], 0.f);
        *(bf16x4*)(stg + m16 * 64 + ((32 * t + 8 * g) ^ SWZ(m16))) = pk;
      }
      bf16x8 sf = *(const bf16x8*)(stg + m16 * 64 + ((16 * g) ^ SWZ(m16)));
      #pragma unroll
      for (int nt3 = 0; nt3 < 3; ++nt3) {
        bf16x8 wf = *(const bf16x8*)(sm + W3OFF + (nt3 * 4 + k2) * 1024 + lane * 16);
        acc3[nt3] = __builtin_amdgcn_mfma_f32_16x16x32_bf16(wf, sf, acc3[nt3], 0, 0, 0);
      }
    }

    // ---- log_softmax over 34 classes (features spread over 4 lane-groups) ----
    float z[12];
    #pragma unroll
    for (int nt3 = 0; nt3 < 3; ++nt3) {
      f32x4 b = *(const f32x4*)(b3p + nt3 * 16 + 4 * g);
      #pragma unroll
      for (int r = 0; r < 4; ++r) {
        const int f = nt3 * 16 + 4 * g + r;
        z[nt3 * 4 + r] = (f < 34) ? (acc3[nt3][r] + b[r]) : -1e30f;
      }
    }
    float mx = z[0];
    #pragma unroll
    for (int i = 1; i < 12; ++i) mx = fmaxf(mx, z[i]);
    mx = fmaxf(mx, __shfl_xor(mx, 16));
    mx = fmaxf(mx, __shfl_xor(mx, 32));
    float sum = 0.f;
    #pragma unroll
    for (int i = 0; i < 12; ++i) sum += __expf(z[i] - mx);
    sum += __shfl_xor(sum, 16);
    sum += __shfl_xor(sum, 32);
    const float lse = mx + __logf(sum);

    float* orow = out + (size_t)(S + m16) * 34;
    *(float2*)(orow +  0 + 4 * g) = make_float2(z[0] - lse, z[1] - lse);
    *(float2*)(orow +  2 + 4 * g) = make_float2(z[2] - lse, z[3] - lse);
    *(float2*)(orow + 16 + 4 * g) = make_float2(z[4] - lse, z[5] - lse);
    *(float2*)(orow + 18 + 4 * g) = make_float2(z[6] - lse, z[7] - lse);
    if (g == 0)
      *(float2*)(orow + 32) = make_float2(z[8] - lse, z[9] - lse);

    if (pf) compact(xn);                     // build next pass's x tile
  }
}

extern "C" void kernel_launch(void* const* d_in, const int* in_sizes, int n_in,
                              void* d_out, int out_size, void* d_ws, size_t ws_size,
                              hipStream_t stream)
{
  const float* node = (const float*)d_in[0];
  const float* edge = (const float*)d_in[1];
  const float* W1   = (const float*)d_in[2];
  const float* b1   = (const float*)d_in[3];
  const float* W2   = (const float*)d_in[4];
  const float* b2   = (const float*)d_in[5];
  const float* W3   = (const float*)d_in[6];
  const float* b3   = (const float*)d_in[7];
  char* img = (char*)d_ws;

  prep_kernel<<<25, 256, 0, stream>>>(W1, b1, W2, b2, W3, b3, img);
  mlp_kernel<<<256, 512, 0, stream>>>(node, edge, img, (float*)d_out);
}